// Round 3
// baseline (664.194 us; speedup 1.0000x reference)
//
#include <hip/hip_runtime.h>

#define T_LEN 512
#define D_DIM 32
#define N_DIM 64
#define B_ALL 128
#define R_TILE 4      // real batch rows per block (M=16 MFMA, rows permuted)
#define M_DIM 16      // MFMA M dimension
#define HSTR 72       // ushort row stride for sHh/sHl: 16B-aligned, bank-spread

typedef short s8v __attribute__((ext_vector_type(8)));   // 8 bf16 (4 VGPRs)
typedef float f4v __attribute__((ext_vector_type(4)));   // MFMA C/D
typedef unsigned int uint;
typedef unsigned short u16;

__device__ __forceinline__ float rcp_f(float x) {
#if __has_builtin(__builtin_amdgcn_rcpf)
    return __builtin_amdgcn_rcpf(x);
#else
    return 1.0f / x;
#endif
}
__device__ __forceinline__ float tanh_f(float x) {
    float e = __expf(2.0f * x);
    return 1.0f - 2.0f * rcp_f(e + 1.0f);
}
__device__ __forceinline__ float sig_f(float x) {
    return rcp_f(1.0f + __expf(-x));
}
__device__ __forceinline__ uint f2bf(float f) {   // fp32 -> bf16 bits, RNE
    uint u = __float_as_uint(f);
    return (u + 0x7FFFu + ((u >> 16) & 1u)) >> 16;
}
__device__ __forceinline__ s8v pack4(uint a, uint b, uint c, uint d_) {
    union { uint u[4]; s8v v; } x;
    x.u[0] = a; x.u[1] = b; x.u[2] = c; x.u[3] = d_;
    return x.v;
}

// Grid 1024 blocks (32 d x 32 row-quads) x 256 thr (4 waves) -> 4 blocks/CU
// = 4 independent waves per SIMD (R2 had 2). Each block owns 4 batch rows;
// M-row permutation puts real row r (0..3) at M index 4r, so lane (quad,col)
// owns exactly ONE real row (= quad) in C reg 0; M rows 4q+1..4q+3 are zero
// rows (never written, never read). Per-wave VALU (gates/h-write/alpha)
// halves vs R2 while MFMA issue per SIMD doubles (96 x ~4.85cy ~ 470cy,
// still below the VALU load), and 4 independent barrier groups per SIMD
// cover each other's barrier/LDS/exp-chain stalls (m114 overlap).
// h double-buffered hi/lo bf16 planes in LDS, direct ds_read_b128 A frags,
// ONE barrier per step. Bitwise-identical arithmetic to R2.
__global__ void __launch_bounds__(256, 4)
imv_lstm_scan(const float* __restrict__ x,
              const float* __restrict__ Uj, const float* __restrict__ Ui,
              const float* __restrict__ Uf, const float* __restrict__ Uo,
              const float* __restrict__ Wj, const float* __restrict__ Wi,
              const float* __restrict__ Wf, const float* __restrict__ Wo,
              const float* __restrict__ bj, const float* __restrict__ bi_,
              const float* __restrict__ bf_, const float* __restrict__ bo,
              const float* __restrict__ Fa, const float* __restrict__ Fab,
              const float* __restrict__ Fbw, const float* __restrict__ Fbb,
              const float* __restrict__ Pw, const float* __restrict__ Pb,
              float* __restrict__ wmu, float* __restrict__ wbeta)
{
    __shared__ float sXT[T_LEN][R_TILE];     // 8 KB, [t][r]
    __shared__ u16   sHh[2][M_DIM][HSTR];    // 4.5 KB, h hi bf16, [buf][Mrow][k]
    __shared__ u16   sHl[2][M_DIM][HSTR];    // 4.5 KB, h lo bf16
    __shared__ float sPS[2][R_TILE][4];      // alpha partials [buf][row][wg]
    __shared__ float sPV[R_TILE][4];         // epilogue second buffer

    const int tid  = threadIdx.x;
    const int lane = tid & 63;
    const int wg   = tid >> 6;               // 0..3 (n-group)
    const int quad = lane >> 4;              // 0..3
    const int col  = lane & 15;
    const int d    = blockIdx.x & 31;
    const int rt   = blockIdx.x >> 5;        // 0..31
    const int r0   = rt * R_TILE;
    const int n    = wg * 16 + col;          // this lane's n
    const int mrow = quad * 4;               // M row of this lane's real row
    const int rrow = quad;                   // this lane's real row (0..3)

    // ---- stage x transposed: sXT[t][r] ----
    for (int i = tid; i < R_TILE * T_LEN; i += 256) {
        int t = i >> 2, r = i & 3;
        sXT[t][r] = x[((size_t)(r0 + r) * T_LEN + t) * D_DIM + d];
    }
    // ---- h0 = 0 (zero both buffers; unwritten M rows stay 0 forever) ----
    for (int i = tid; i < 2 * M_DIM * HSTR; i += 256) {
        ((u16*)sHh)[i] = 0; ((u16*)sHl)[i] = 0;
    }

    // ---- W fragments into registers: Bh/Bl[gate][k-chunk] ----
    s8v Bh[4][2], Bl[4][2];
    #pragma unroll
    for (int g = 0; g < 4; ++g) {
        const float* Wg = (g == 0 ? Wj : g == 1 ? Wi : g == 2 ? Wf : Wo)
                          + d * (N_DIM * N_DIM);
        #pragma unroll
        for (int c = 0; c < 2; ++c) {
            uint hp[4], lp[4];
            #pragma unroll
            for (int jp = 0; jp < 4; ++jp) {
                float w0 = Wg[(32 * c + quad * 8 + 2 * jp + 0) * N_DIM + n];
                float w1 = Wg[(32 * c + quad * 8 + 2 * jp + 1) * N_DIM + n];
                uint u0 = __float_as_uint(w0), u1 = __float_as_uint(w1);
                uint h0b = u0 & 0xFFFF0000u, h1b = u1 & 0xFFFF0000u;
                float l0 = w0 - __uint_as_float(h0b);
                float l1 = w1 - __uint_as_float(h1b);
                hp[jp] = (u0 >> 16) | h1b;
                lp[jp] = f2bf(l0) | (f2bf(l1) << 16);
            }
            Bh[g][c] = pack4(hp[0], hp[1], hp[2], hp[3]);
            Bl[g][c] = pack4(lp[0], lp[1], lp[2], lp[3]);
        }
    }

    const int dn = d * N_DIM + n;
    const float u_j = Uj[dn], u_i = Ui[dn], u_f = Uf[dn], u_o = Uo[dn];
    const float cbj = bj[dn], cbi = bi_[dn], cbf = bf_[dn], cbo = bo[dn];
    const float fan = Fa[dn];
    const float fab = Fab[d];

    __syncthreads();

    float c_ = 0.f, h_ = 0.f, ga = 0.f, as = 0.f;

    #pragma unroll 2
    for (int t = 0; t < T_LEN; ++t) {
        const int wb = t & 1;        // write buffer (h_t)
        const int rb = wb ^ 1;       // read buffer (h_{t-1})

        // ---- A fragments: direct b128 reads, zero unpack ----
        s8v Ah[2], Al[2];
        #pragma unroll
        for (int c = 0; c < 2; ++c) {
            Ah[c] = *(const s8v*)&sHh[rb][col][32 * c + quad * 8];
            Al[c] = *(const s8v*)&sHl[rb][col][32 * c + quad * 8];
        }

        // ---- 24 MFMAs: 4 gates x 2 k-chunks x 3 hi/lo terms ----
        f4v acc[4];
        #pragma unroll
        for (int g = 0; g < 4; ++g) {
            f4v a = {0.f, 0.f, 0.f, 0.f};
            #pragma unroll
            for (int c = 0; c < 2; ++c) {
                a = __builtin_amdgcn_mfma_f32_16x16x32_bf16(Ah[c], Bh[g][c], a, 0, 0, 0);
                a = __builtin_amdgcn_mfma_f32_16x16x32_bf16(Al[c], Bh[g][c], a, 0, 0, 0);
                a = __builtin_amdgcn_mfma_f32_16x16x32_bf16(Ah[c], Bl[g][c], a, 0, 0, 0);
            }
            acc[g] = a;
        }

        // ---- stage 3: C reg 0 = real row rrow (= quad) at n ----
        {
            float xv = sXT[t][rrow];
            float jp = acc[0][0] + fmaf(xv, u_j, cbj);
            float ip = acc[1][0] + fmaf(xv, u_i, cbi);
            float fp = acc[2][0] + fmaf(xv, u_f, cbf);
            float op = acc[3][0] + fmaf(xv, u_o, cbo);
            c_ = fmaf(c_, sig_f(fp), sig_f(ip) * tanh_f(jp));
            h_ = sig_f(op) * tanh_f(c_);
        }
        float ps = h_ * fan;
        // reduce ps over this wave's 16 n (stays within quad-group)
        ps += __shfl_xor(ps, 1);
        ps += __shfl_xor(ps, 2);
        ps += __shfl_xor(ps, 4);
        ps += __shfl_xor(ps, 8);

        // ---- write h_t (hi/lo planes, M row mrow) + alpha partials ----
        {
            uint u = __float_as_uint(h_);
            uint hb = u & 0xFFFF0000u;
            float lo = h_ - __uint_as_float(hb);
            sHh[wb][mrow][n] = (u16)(u >> 16);
            sHl[wb][mrow][n] = (u16)f2bf(lo);
        }
        if (col == 0)
            sPS[wb][rrow][wg] = ps;

        __syncthreads();   // the ONLY barrier: h_t and partials visible

        {
            f4v tv = *(const f4v*)&sPS[wb][rrow][0];
            float tot = tv[0] + tv[1] + tv[2] + tv[3];
            float al = __expf(tanh_f(tot + fab));
            as += al;
            ga = fmaf(al, h_, ga);
        }
    }

    // ---- epilogue: mu, beta per (row, d) ----
    const float pwa = Pw[n],  pwb = Pw[64 + n];
    const float fwa = Fbw[n], fwb = Fbw[64 + n];
    float gn = ga * rcp_f(as);
    float pm = fmaf(gn, pwa, h_ * pwb);
    float pv = fmaf(gn, fwa, h_ * fwb);
    pm += __shfl_xor(pm, 1); pm += __shfl_xor(pm, 2);
    pm += __shfl_xor(pm, 4); pm += __shfl_xor(pm, 8);
    pv += __shfl_xor(pv, 1); pv += __shfl_xor(pv, 2);
    pv += __shfl_xor(pv, 4); pv += __shfl_xor(pv, 8);
    __syncthreads();   // in-loop sPS reads done
    if (col == 0) {
        sPS[0][rrow][wg] = pm;
        sPV[rrow][wg]    = pv;
    }
    __syncthreads();
    if (tid < R_TILE) {
        int r = tid;
        f4v a  = *(const f4v*)&sPS[0][r][0];
        f4v b2 = *(const f4v*)&sPV[r][0];
        float mu = a[0] + a[1] + a[2] + a[3] + Pb[0];
        float bt = __expf(tanh_f(b2[0] + b2[1] + b2[2] + b2[3] + Fbb[0]));
        wmu  [(r0 + r) * D_DIM + d] = mu;
        wbeta[(r0 + r) * D_DIM + d] = bt;
    }
}

// beta softmax over d + weighted sum -> out[b]
__global__ void imv_finalize(const float* __restrict__ wmu,
                             const float* __restrict__ wbeta,
                             float* __restrict__ out)
{
    int b = blockIdx.x * 64 + threadIdx.x;
    if (b >= B_ALL) return;
    float s1 = 0.f, s2 = 0.f;
    for (int d = 0; d < D_DIM; ++d) {
        float be = wbeta[b * D_DIM + d];
        s1 = fmaf(be, wmu[b * D_DIM + d], s1);
        s2 += be;
    }
    out[b] = s1 / s2;
}

extern "C" void kernel_launch(void* const* d_in, const int* in_sizes, int n_in,
                              void* d_out, int out_size, void* d_ws, size_t ws_size,
                              hipStream_t stream)
{
    const float* x   = (const float*)d_in[0];
    const float* U_j = (const float*)d_in[1];
    const float* U_i = (const float*)d_in[2];
    const float* U_f = (const float*)d_in[3];
    const float* U_o = (const float*)d_in[4];
    const float* W_j = (const float*)d_in[5];
    const float* W_i = (const float*)d_in[6];
    const float* W_f = (const float*)d_in[7];
    const float* W_o = (const float*)d_in[8];
    const float* b_j = (const float*)d_in[9];
    const float* b_i = (const float*)d_in[10];
    const float* b_f = (const float*)d_in[11];
    const float* b_o = (const float*)d_in[12];
    const float* Fan  = (const float*)d_in[13];
    const float* Fanb = (const float*)d_in[14];
    const float* Fbw  = (const float*)d_in[15];
    const float* Fbb  = (const float*)d_in[16];
    const float* Phw  = (const float*)d_in[17];
    const float* Phb  = (const float*)d_in[18];

    float* wmu   = (float*)d_ws;
    float* wbeta = wmu + B_ALL * D_DIM;

    imv_lstm_scan<<<dim3(1024), dim3(256), 0, stream>>>(
        x, U_j, U_i, U_f, U_o, W_j, W_i, W_f, W_o,
        b_j, b_i, b_f, b_o, Fan, Fanb, Fbw, Fbb, Phw, Phb,
        wmu, wbeta);

    imv_finalize<<<dim3(2), dim3(64), 0, stream>>>(wmu, wbeta, (float*)d_out);
}